// Round 1
// baseline (3070.454 us; speedup 1.0000x reference)
//
#include <hip/hip_runtime.h>
#include <math.h>

#define MAXNORM_F 0.996f

__device__ __forceinline__ float artanh_c(float x) {
    const float lim = 1.0f - 1e-5f;
    x = fminf(fmaxf(x, -lim), lim);
    return 0.5f * logf((1.0f + x) / (1.0f - x));
}

__device__ __forceinline__ float block_reduce_sum(float v, float* red) {
    int tid = threadIdx.x;
    red[tid] = v;
    __syncthreads();
    for (int s = 128; s > 0; s >>= 1) {
        if (tid < s) red[tid] += red[tid + s];
        __syncthreads();
    }
    float r = red[0];
    __syncthreads();
    return r;
}

// ---------------- prep: zscore per block + concat + expmap0 ----------------
__global__ __launch_bounds__(256) void prep_kernel(
    const float* __restrict__ s0, const float* __restrict__ s1,
    const float* __restrict__ s2, const float* __restrict__ s3,
    int f0, int f1, int f2, int f3,
    float* __restrict__ X, float* __restrict__ xn_out) {
    __shared__ float xbuf[1712];
    __shared__ float red[256];
    const int row = blockIdx.x;
    const int tid = threadIdx.x;
    const float* srcs[4] = {s0, s1, s2, s3};
    const int fs[4] = {f0, f1, f2, f3};
    int off = 0;
    for (int b = 0; b < 4; b++) {
        int F = fs[b];
        if (F == 0) break;
        const float* srow = srcs[b] + (size_t)row * F;
        float ps = 0.f;
        for (int i = tid; i < F; i += 256) { float v = srow[i]; xbuf[off + i] = v; ps += v; }
        float mean = block_reduce_sum(ps, red) / (float)F;
        float pq = 0.f;
        for (int i = tid; i < F; i += 256) { float d = xbuf[off + i] - mean; pq += d * d; }
        float var = block_reduce_sum(pq, red) / (float)(F - 1);
        float inv = 1.0f / (sqrtf(var) + 1e-8f);
        for (int i = tid; i < F; i += 256) xbuf[off + i] = (xbuf[off + i] - mean) * inv;
        off += F;
    }
    __syncthreads();
    // expmap0 over the concatenated 1711-vector
    float pn = 0.f;
    for (int i = tid; i < 1711; i += 256) pn += xbuf[i] * xbuf[i];
    float n = fmaxf(sqrtf(block_reduce_sum(pn, red)), 1e-15f);
    float t = tanhf(n);
    float sc = t / n;
    float* xrow = X + (size_t)row * 1712;
    for (int i = tid; i < 1711; i += 256) xrow[i] = sc * xbuf[i];
    if (tid == 0) { xrow[1711] = 0.f; xn_out[row] = fmaxf(t, 1e-15f); }
}

// ---------------- fp32 tiled GEMM: C[M,N] = A[M,K] @ W[K,N] ----------------
// A has leading dim lda (zero-padded so Kpad%16==0, lda>=Kpad, lda%4==0).
__global__ __launch_bounds__(256) void gemm_kernel(
    const float* __restrict__ A, int lda,
    const float* __restrict__ W, int N, int Kreal, int Kpad,
    float* __restrict__ C) {
    __shared__ float As[16][64];
    __shared__ float Bs[16][64];
    const int tid = threadIdx.x;
    const int tx = tid & 15, ty = tid >> 4;
    const int m0 = blockIdx.y * 64, n0 = blockIdx.x * 64;
    const int am = tid >> 2;          // 0..63
    const int ak = (tid & 3) * 4;     // 0,4,8,12
    const int wk = tid >> 4;          // 0..15
    const int wn = (tid & 15) * 4;    // 0..60
    float acc[4][4];
#pragma unroll
    for (int i = 0; i < 4; i++)
#pragma unroll
        for (int j = 0; j < 4; j++) acc[i][j] = 0.f;

    for (int k0 = 0; k0 < Kpad; k0 += 16) {
        float4 av = *(const float4*)(A + (size_t)(m0 + am) * lda + k0 + ak);
        As[ak + 0][am] = av.x; As[ak + 1][am] = av.y;
        As[ak + 2][am] = av.z; As[ak + 3][am] = av.w;
        float4 wv;
        if (k0 + wk < Kreal) wv = *(const float4*)(W + (size_t)(k0 + wk) * N + n0 + wn);
        else wv = make_float4(0.f, 0.f, 0.f, 0.f);
        *(float4*)&Bs[wk][wn] = wv;
        __syncthreads();
#pragma unroll
        for (int k = 0; k < 16; k++) {
            float4 a = *(const float4*)&As[k][ty * 4];
            float4 b = *(const float4*)&Bs[k][tx * 4];
            float ar[4] = {a.x, a.y, a.z, a.w};
            float br[4] = {b.x, b.y, b.z, b.w};
#pragma unroll
            for (int i = 0; i < 4; i++)
#pragma unroll
                for (int j = 0; j < 4; j++) acc[i][j] += ar[i] * br[j];
        }
        __syncthreads();
    }
#pragma unroll
    for (int i = 0; i < 4; i++) {
        float4 o = make_float4(acc[i][0], acc[i][1], acc[i][2], acc[i][3]);
        *(float4*)(C + (size_t)(m0 + ty * 4 + i) * N + n0 + tx * 4) = o;
    }
}

// ---------------- hyperbolic linear epilogue (register-resident) ----------------
// v holds mx elements at indices tid + j*256 (< N). Returns post-op row norm.
template<int EPT>
__device__ float hyper_head(float (&v)[EPT], const float (&bv)[EPT], int N, float xn,
                            int do_tanh, float* red) {
    const int tid = threadIdx.x;
    // mobius_matvec scale
    float p = 0.f;
#pragma unroll
    for (int j = 0; j < EPT; j++) if (tid + j * 256 < N) p += v[j] * v[j];
    float mxn = fmaxf(sqrtf(block_reduce_sum(p, red)), 1e-15f);
    float t1 = tanhf((mxn / xn) * artanh_c(xn));      // >= 0
    float ny = fmaxf(t1, 1e-15f);
    float fac = (ny > MAXNORM_F) ? (MAXNORM_F / ny) : 1.0f;   // projx after matvec
    float sm = t1 * fac / mxn;
    // y = sm*mx ; mobius_add(y, b)
    float pa2 = 0.f, pab = 0.f, pb2 = 0.f;
#pragma unroll
    for (int j = 0; j < EPT; j++) {
        v[j] *= sm;
        if (tid + j * 256 < N) { pa2 += v[j] * v[j]; pab += v[j] * bv[j]; pb2 += bv[j] * bv[j]; }
    }
    float a2 = block_reduce_sum(pa2, red);
    float ab = block_reduce_sum(pab, red);
    float b2 = block_reduce_sum(pb2, red);
    float den = fmaxf(1.0f + 2.0f * ab + a2 * b2, 1e-15f);
    float ca = (1.0f + 2.0f * ab + b2) / den;
    float cb = (1.0f - a2) / den;
    float pz2 = 0.f;
#pragma unroll
    for (int j = 0; j < EPT; j++) {
        v[j] = ca * v[j] + cb * bv[j];
        if (tid + j * 256 < N) pz2 += v[j] * v[j];
    }
    float nz = fmaxf(sqrtf(block_reduce_sum(pz2, red)), 1e-15f);
    float fz = (nz > MAXNORM_F) ? (MAXNORM_F / nz) : 1.0f;    // projx after add
    float nzp = nz * fz;
    if (!do_tanh) {
#pragma unroll
        for (int j = 0; j < EPT; j++) v[j] *= fz;
        return nzp;
    }
    // mobius_tanh: logmap0 -> tanh -> expmap0 -> projx
    float ia = artanh_c(nzp) / nzp * fz;
    float pt2 = 0.f;
#pragma unroll
    for (int j = 0; j < EPT; j++) {
        v[j] = tanhf(ia * v[j]);
        if (tid + j * 256 < N) pt2 += v[j] * v[j];
    }
    float ntn = fmaxf(sqrtf(block_reduce_sum(pt2, red)), 1e-15f);
    float to = tanhf(ntn);
    float no = fmaxf(to, 1e-15f);
    float fo = (no > MAXNORM_F) ? (MAXNORM_F / no) : 1.0f;
    float so = to / ntn * fo;
#pragma unroll
    for (int j = 0; j < EPT; j++) v[j] *= so;
    return fminf(no, MAXNORM_F);
}

template<int EPT>
__global__ __launch_bounds__(256) void epi_kernel(
    const float* __restrict__ MX, int N, const float* __restrict__ bias,
    float* __restrict__ xn_io, float* __restrict__ Xout, int do_tanh) {
    __shared__ float red[256];
    const int row = blockIdx.x, tid = threadIdx.x;
    const float* mrow = MX + (size_t)row * N;
    float v[EPT], bv[EPT];
#pragma unroll
    for (int j = 0; j < EPT; j++) { v[j] = mrow[tid + j * 256]; bv[j] = bias[tid + j * 256]; }
    float xn = xn_io[row];
    float nrm = hyper_head<EPT>(v, bv, N, xn, do_tanh, red);
    float* orow = Xout + (size_t)row * N;
#pragma unroll
    for (int j = 0; j < EPT; j++) orow[tid + j * 256] = v[j];
    if (tid == 0) xn_io[row] = nrm;
}

// ---------------- merge (scalar_mul + mobius_add + projx) + 3-layer MLP ----------------
__global__ __launch_bounds__(256) void merge_mlp_kernel(
    const float* __restrict__ head, const float* __restrict__ tail,
    const float* __restrict__ nh_arr, const float* __restrict__ nt_arr,
    const float* __restrict__ Wm1, const float* __restrict__ bm1,
    const float* __restrict__ Wm2, const float* __restrict__ bm2,
    const float* __restrict__ Wm3, const float* __restrict__ bm3,
    float* __restrict__ out) {
    __shared__ float xs[256];
    __shared__ float red[256];
    const int row = blockIdx.x, tid = threadIdx.x;
    float h = head[(size_t)row * 256 + tid];
    float t = tail[(size_t)row * 256 + tid];
    float nh = nh_arr[row], ntl = nt_arr[row];
    float sh = tanhf(0.27f * artanh_c(nh)) / nh;
    float st = tanhf(0.73f * artanh_c(ntl)) / ntl;
    float A = sh * h, Bv = st * t;
    float x2 = block_reduce_sum(A * A, red);
    float y2 = block_reduce_sum(Bv * Bv, red);
    float xy = block_reduce_sum(A * Bv, red);
    float den = fmaxf(1.0f + 2.0f * xy + x2 * y2, 1e-15f);
    float z = ((1.0f + 2.0f * xy + y2) * A + (1.0f - x2) * Bv) / den;
    float nz = fmaxf(sqrtf(block_reduce_sum(z * z, red)), 1e-15f);
    float fz = (nz > MAXNORM_F) ? (MAXNORM_F / nz) : 1.0f;
    float nmid = nz * fz;
    xs[tid] = z * fz;
    __syncthreads();

    float v[1], bv[1];
    // layer 1: K=256 -> N=64, tanh
    v[0] = 0.f; bv[0] = 0.f;
    if (tid < 64) {
        float acc = 0.f;
        for (int k = 0; k < 256; k++) acc += xs[k] * Wm1[k * 64 + tid];
        v[0] = acc; bv[0] = bm1[tid];
    }
    float n1 = hyper_head<1>(v, bv, 64, nmid, 1, red);
    __syncthreads();
    if (tid < 64) xs[tid] = v[0];
    __syncthreads();
    // layer 2: K=64 -> N=32, tanh
    v[0] = 0.f; bv[0] = 0.f;
    if (tid < 32) {
        float acc = 0.f;
        for (int k = 0; k < 64; k++) acc += xs[k] * Wm2[k * 32 + tid];
        v[0] = acc; bv[0] = bm2[tid];
    }
    float n2 = hyper_head<1>(v, bv, 32, n1, 1, red);
    __syncthreads();
    if (tid < 32) xs[tid] = v[0];
    __syncthreads();
    // layer 3: K=32 -> N=2, no tanh
    v[0] = 0.f; bv[0] = 0.f;
    if (tid < 2) {
        float acc = 0.f;
        for (int k = 0; k < 32; k++) acc += xs[k] * Wm3[k * 2 + tid];
        v[0] = acc; bv[0] = bm3[tid];
    }
    hyper_head<1>(v, bv, 2, n2, 0, red);
    if (tid < 2) out[(size_t)row * 2 + tid] = v[0];
}

// ---------------- launch ----------------
extern "C" void kernel_launch(void* const* d_in, const int* in_sizes, int n_in,
                              void* d_out, int out_size, void* d_ws, size_t ws_size,
                              hipStream_t stream) {
    const float* dch = (const float*)d_in[0];
    const float* dpc = (const float*)d_in[1];
    const float* dmc = (const float*)d_in[2];
    const float* dec = (const float*)d_in[3];
    const float* tes = (const float*)d_in[4];
    const float* tpc = (const float*)d_in[5];
    const float* tme = (const float*)d_in[6];
    const float* Wd1 = (const float*)d_in[7];  const float* bd1 = (const float*)d_in[8];
    const float* Wd2 = (const float*)d_in[9];  const float* bd2 = (const float*)d_in[10];
    const float* Wd3 = (const float*)d_in[11]; const float* bd3 = (const float*)d_in[12];
    const float* Wt1 = (const float*)d_in[13]; const float* bt1 = (const float*)d_in[14];
    const float* Wt2 = (const float*)d_in[15]; const float* bt2 = (const float*)d_in[16];
    const float* Wt3 = (const float*)d_in[17]; const float* bt3 = (const float*)d_in[18];
    const float* Wm1 = (const float*)d_in[19]; const float* bm1 = (const float*)d_in[20];
    const float* Wm2 = (const float*)d_in[21]; const float* bm2 = (const float*)d_in[22];
    const float* Wm3 = (const float*)d_in[23]; const float* bm3 = (const float*)d_in[24];

    const int B = in_sizes[0] / 768;   // 16384
    float* ws = (float*)d_ws;
    float* x_d  = ws;                              // B*1712
    float* x_t  = x_d + (size_t)B * 1712;          // B*1712
    float* mx   = x_t + (size_t)B * 1712;          // B*1024
    float* xn_d = mx + (size_t)B * 1024;           // B
    float* xn_t = xn_d + B;                        // B

    dim3 blk(256);
    // prep both branches
    hipLaunchKernelGGL(prep_kernel, dim3(B), blk, 0, stream,
                       dch, dpc, dmc, dec, 768, 11, 167, 765, x_d, xn_d);
    hipLaunchKernelGGL(prep_kernel, dim3(B), blk, 0, stream,
                       tes, tpc, tme, (const float*)nullptr, 1280, 11, 420, 0, x_t, xn_t);
    // drug branch
    hipLaunchKernelGGL(gemm_kernel, dim3(1024 / 64, B / 64), blk, 0, stream,
                       x_d, 1712, Wd1, 1024, 1711, 1712, mx);
    hipLaunchKernelGGL((epi_kernel<4>), dim3(B), blk, 0, stream, mx, 1024, bd1, xn_d, x_d, 1);
    hipLaunchKernelGGL(gemm_kernel, dim3(512 / 64, B / 64), blk, 0, stream,
                       x_d, 1024, Wd2, 512, 1024, 1024, mx);
    hipLaunchKernelGGL((epi_kernel<2>), dim3(B), blk, 0, stream, mx, 512, bd2, xn_d, x_d, 1);
    hipLaunchKernelGGL(gemm_kernel, dim3(256 / 64, B / 64), blk, 0, stream,
                       x_d, 512, Wd3, 256, 512, 512, mx);
    hipLaunchKernelGGL((epi_kernel<1>), dim3(B), blk, 0, stream, mx, 256, bd3, xn_d, x_d, 0);
    // target branch
    hipLaunchKernelGGL(gemm_kernel, dim3(1024 / 64, B / 64), blk, 0, stream,
                       x_t, 1712, Wt1, 1024, 1711, 1712, mx);
    hipLaunchKernelGGL((epi_kernel<4>), dim3(B), blk, 0, stream, mx, 1024, bt1, xn_t, x_t, 1);
    hipLaunchKernelGGL(gemm_kernel, dim3(512 / 64, B / 64), blk, 0, stream,
                       x_t, 1024, Wt2, 512, 1024, 1024, mx);
    hipLaunchKernelGGL((epi_kernel<2>), dim3(B), blk, 0, stream, mx, 512, bt2, xn_t, x_t, 1);
    hipLaunchKernelGGL(gemm_kernel, dim3(256 / 64, B / 64), blk, 0, stream,
                       x_t, 512, Wt3, 256, 512, 512, mx);
    hipLaunchKernelGGL((epi_kernel<1>), dim3(B), blk, 0, stream, mx, 256, bt3, xn_t, x_t, 0);
    // merge + MLP -> out
    hipLaunchKernelGGL(merge_mlp_kernel, dim3(B), blk, 0, stream,
                       x_d, x_t, xn_d, xn_t, Wm1, bm1, Wm2, bm2, Wm3, bm3, (float*)d_out);
}

// Round 3
// 1779.424 us; speedup vs baseline: 1.7255x; 1.7255x over previous
//
#include <hip/hip_runtime.h>
#include <math.h>

#define MAXNORM_F 0.996f

typedef __attribute__((ext_vector_type(8))) short bf16x8;
typedef __attribute__((ext_vector_type(4))) float f32x4;

__device__ __forceinline__ short f2bf(float f) {
    union { float f; unsigned u; } v; v.f = f;
    unsigned r = v.u + 0x7FFF + ((v.u >> 16) & 1);
    return (short)(r >> 16);
}
__device__ __forceinline__ float bf2f(short s) {
    union { unsigned u; float f; } v; v.u = ((unsigned)(unsigned short)s) << 16;
    return v.f;
}

__device__ __forceinline__ float artanh_c(float x) {
    const float lim = 1.0f - 1e-5f;
    x = fminf(fmaxf(x, -lim), lim);
    return 0.5f * logf((1.0f + x) / (1.0f - x));
}

__device__ __forceinline__ float block_reduce_sum(float v, float* red) {
    int tid = threadIdx.x;
    red[tid] = v;
    __syncthreads();
    for (int s = 128; s > 0; s >>= 1) {
        if (tid < s) red[tid] += red[tid + s];
        __syncthreads();
    }
    float r = red[0];
    __syncthreads();
    return r;
}

// ---- weight pack: fp32 [K][N] -> bf16 [ntile][kbp][kg][n][j], kbp over 3*KB ----
// segment 0: Wh, segment 1: Wh (pairs with A-lo), segment 2: Wl (pairs with A-hi)
__global__ __launch_bounds__(256) void pack_w_kernel(
    const float* __restrict__ W, int Kreal, int KB, int KBtot, int N,
    short* __restrict__ out) {
    int e = blockIdx.x * 256 + threadIdx.x;
    int total = (N >> 7) * KBtot * 4096;
    if (e >= total) return;
    int j  = e & 7;
    int n  = (e >> 3) & 127;
    int kg = (e >> 10) & 3;
    int rest = e >> 12;
    int kbp = rest % KBtot;
    int nt  = rest / KBtot;
    int kloc_blk = (kbp < KB) ? kbp : ((kbp < 2 * KB) ? kbp - KB : kbp - 2 * KB);
    int k = (kloc_blk << 5) + (kg << 3) + j;
    int col = (nt << 7) + n;
    float v = (k < Kreal) ? W[(size_t)k * N + col] : 0.f;
    short hi = f2bf(v);
    out[e] = (kbp < 2 * KB) ? hi : f2bf(v - bf2f(hi));
}

// ---- prep: zscore + concat + expmap0 -> bf16 hi|lo split row ----
__global__ __launch_bounds__(256) void prep_kernel(
    const float* __restrict__ s0, const float* __restrict__ s1,
    const float* __restrict__ s2, const float* __restrict__ s3,
    int f0, int f1, int f2, int f3,
    short* __restrict__ Xb, float* __restrict__ xn_out) {
    __shared__ float xbuf[1712];
    __shared__ float red[256];
    const int row = blockIdx.x;
    const int tid = threadIdx.x;
    const float* srcs[4] = {s0, s1, s2, s3};
    const int fs[4] = {f0, f1, f2, f3};
    int off = 0;
    for (int b = 0; b < 4; b++) {
        int F = fs[b];
        if (F == 0) break;
        const float* srow = srcs[b] + (size_t)row * F;
        float ps = 0.f;
        for (int i = tid; i < F; i += 256) { float v = srow[i]; xbuf[off + i] = v; ps += v; }
        float mean = block_reduce_sum(ps, red) / (float)F;
        float pq = 0.f;
        for (int i = tid; i < F; i += 256) { float d = xbuf[off + i] - mean; pq += d * d; }
        float var = block_reduce_sum(pq, red) / (float)(F - 1);
        float inv = 1.0f / (sqrtf(var) + 1e-8f);
        for (int i = tid; i < F; i += 256) xbuf[off + i] = (xbuf[off + i] - mean) * inv;
        off += F;
    }
    __syncthreads();
    float pn = 0.f;
    for (int i = tid; i < 1711; i += 256) pn += xbuf[i] * xbuf[i];
    float n = fmaxf(sqrtf(block_reduce_sum(pn, red)), 1e-15f);
    float t = tanhf(n);
    float sc = t / n;
    short* xrow = Xb + (size_t)row * 3456;   // [hi(1728) | lo(1728)]
    for (int i = tid; i < 1711; i += 256) {
        float v = sc * xbuf[i];
        short hi = f2bf(v);
        xrow[i] = hi;
        xrow[1728 + i] = f2bf(v - bf2f(hi));
    }
    if (tid < 17) { xrow[1711 + tid] = 0; xrow[1728 + 1711 + tid] = 0; }
    if (tid == 0) xn_out[row] = fmaxf(t, 1e-15f);
}

// ---- bf16 MFMA GEMM with split-K remap: C = A'[hi|lo] @ W'[Wh|Wh|Wl] ----
// A: bf16 [M][lda], lda = 2*Kpad. K-blocks kb in [0,KBtot=3*KB):
//   kb < 2*KB reads A at block kb (hi then lo); kb >= 2*KB re-reads hi at kb-2*KB.
__global__ __launch_bounds__(256) void gemm_mfma(
    const short* __restrict__ A, int lda, int KB,
    const short* __restrict__ Wp, int KBtot,
    float* __restrict__ C, int N) {
    __shared__ short As[4096];  // 128 rows x 32 k, 16B units: u = row*4 + (kg^(row&3))
    __shared__ short Bs[4096];  // [kg(4)][n(128)][j(8)]
    const int tid = threadIdx.x;
    const int lane = tid & 63;
    const int wave = __builtin_amdgcn_readfirstlane(tid >> 6);
    const int waveM = wave >> 1, waveN = wave & 1;
    const int m0 = blockIdx.y * 128;
    const int kg = lane >> 4, l16 = lane & 15;

    f32x4 acc[4][4] = {};
    const short* Bbase = Wp + ((size_t)blockIdx.x * KBtot) * 4096;

    for (int kb = 0; kb < KBtot; kb++) {
        int akb = (kb >= 2 * KB) ? (kb - 2 * KB) : kb;
#pragma unroll
        for (int c2 = 0; c2 < 2; c2++) {
            int c = wave * 2 + c2;
            int u = c * 64 + lane;
            int row = u >> 2;
            int k8 = (u & 3) ^ (row & 3);
            const short* ga = A + (size_t)(m0 + row) * lda + (akb << 5) + (k8 << 3);
            __builtin_amdgcn_global_load_lds(
                (const __attribute__((address_space(1))) unsigned int*)ga,
                (__attribute__((address_space(3))) unsigned int*)&As[c * 512],
                16, 0, 0);
        }
#pragma unroll
        for (int c2 = 0; c2 < 2; c2++) {
            int c = wave * 2 + c2;
            const short* gb = Bbase + (size_t)kb * 4096 + c * 512 + lane * 8;
            __builtin_amdgcn_global_load_lds(
                (const __attribute__((address_space(1))) unsigned int*)gb,
                (__attribute__((address_space(3))) unsigned int*)&Bs[c * 512],
                16, 0, 0);
        }
        __syncthreads();
        bf16x8 af[4], bfr[4];
#pragma unroll
        for (int mi = 0; mi < 4; mi++) {
            int row = waveM * 64 + mi * 16 + l16;
            int u = row * 4 + (kg ^ (row & 3));
            af[mi] = *(const bf16x8*)&As[u * 8];
        }
#pragma unroll
        for (int ni = 0; ni < 4; ni++) {
            int n = waveN * 64 + ni * 16 + l16;
            bfr[ni] = *(const bf16x8*)&Bs[(kg * 128 + n) * 8];
        }
#pragma unroll
        for (int mi = 0; mi < 4; mi++)
#pragma unroll
            for (int ni = 0; ni < 4; ni++)
                acc[mi][ni] = __builtin_amdgcn_mfma_f32_16x16x32_bf16(
                    af[mi], bfr[ni], acc[mi][ni], 0, 0, 0);
        __syncthreads();
    }
    const int rbase = m0 + waveM * 64 + (lane >> 4) * 4;
    const int cbase = blockIdx.x * 128 + waveN * 64 + l16;
#pragma unroll
    for (int mi = 0; mi < 4; mi++)
#pragma unroll
        for (int ni = 0; ni < 4; ni++)
#pragma unroll
            for (int r = 0; r < 4; r++)
                C[(size_t)(rbase + mi * 16 + r) * N + cbase + ni * 16] = acc[mi][ni][r];
}

// ---- hyperbolic linear epilogue (fp32 math) ----
template<int EPT>
__device__ float hyper_head(float (&v)[EPT], const float (&bv)[EPT], int N, float xn,
                            int do_tanh, float* red) {
    const int tid = threadIdx.x;
    float p = 0.f;
#pragma unroll
    for (int j = 0; j < EPT; j++) if (tid + j * 256 < N) p += v[j] * v[j];
    float mxn = fmaxf(sqrtf(block_reduce_sum(p, red)), 1e-15f);
    float t1 = tanhf((mxn / xn) * artanh_c(xn));
    float ny = fmaxf(t1, 1e-15f);
    float fac = (ny > MAXNORM_F) ? (MAXNORM_F / ny) : 1.0f;
    float sm = t1 * fac / mxn;
    float pa2 = 0.f, pab = 0.f, pb2 = 0.f;
#pragma unroll
    for (int j = 0; j < EPT; j++) {
        v[j] *= sm;
        if (tid + j * 256 < N) { pa2 += v[j] * v[j]; pab += v[j] * bv[j]; pb2 += bv[j] * bv[j]; }
    }
    float a2 = block_reduce_sum(pa2, red);
    float ab = block_reduce_sum(pab, red);
    float b2 = block_reduce_sum(pb2, red);
    float den = fmaxf(1.0f + 2.0f * ab + a2 * b2, 1e-15f);
    float ca = (1.0f + 2.0f * ab + b2) / den;
    float cb = (1.0f - a2) / den;
    float pz2 = 0.f;
#pragma unroll
    for (int j = 0; j < EPT; j++) {
        v[j] = ca * v[j] + cb * bv[j];
        if (tid + j * 256 < N) pz2 += v[j] * v[j];
    }
    float nz = fmaxf(sqrtf(block_reduce_sum(pz2, red)), 1e-15f);
    float fz = (nz > MAXNORM_F) ? (MAXNORM_F / nz) : 1.0f;
    float nzp = nz * fz;
    if (!do_tanh) {
#pragma unroll
        for (int j = 0; j < EPT; j++) v[j] *= fz;
        return nzp;
    }
    float ia = artanh_c(nzp) / nzp * fz;
    float pt2 = 0.f;
#pragma unroll
    for (int j = 0; j < EPT; j++) {
        v[j] = tanhf(ia * v[j]);
        if (tid + j * 256 < N) pt2 += v[j] * v[j];
    }
    float ntn = fmaxf(sqrtf(block_reduce_sum(pt2, red)), 1e-15f);
    float to = tanhf(ntn);
    float no = fmaxf(to, 1e-15f);
    float fo = (no > MAXNORM_F) ? (MAXNORM_F / no) : 1.0f;
    float so = to / ntn * fo;
#pragma unroll
    for (int j = 0; j < EPT; j++) v[j] *= so;
    return fminf(no, MAXNORM_F);
}

// Writes either bf16 hi|lo split rows (Xout, stride ldx, lo at +off) or fp32 rows (Fout).
template<int EPT>
__global__ __launch_bounds__(256) void epi_kernel(
    const float* __restrict__ MX, int N, const float* __restrict__ bias,
    float* __restrict__ xn_io, short* __restrict__ Xout, int ldx, int off,
    float* __restrict__ Fout, int do_tanh) {
    __shared__ float red[256];
    const int row = blockIdx.x, tid = threadIdx.x;
    const float* mrow = MX + (size_t)row * N;
    float v[EPT], bv[EPT];
#pragma unroll
    for (int j = 0; j < EPT; j++) { v[j] = mrow[tid + j * 256]; bv[j] = bias[tid + j * 256]; }
    float xn = xn_io[row];
    float nrm = hyper_head<EPT>(v, bv, N, xn, do_tanh, red);
    if (Xout) {
        short* orow = Xout + (size_t)row * ldx;
#pragma unroll
        for (int j = 0; j < EPT; j++) {
            int idx = tid + j * 256;
            short hi = f2bf(v[j]);
            orow[idx] = hi;
            orow[off + idx] = f2bf(v[j] - bf2f(hi));
        }
    }
    if (Fout) {
        float* orow = Fout + (size_t)row * N;
#pragma unroll
        for (int j = 0; j < EPT; j++) orow[tid + j * 256] = v[j];
    }
    if (tid == 0) xn_io[row] = fmaxf(nrm, 1e-15f);
}

// ---- merge + 3-layer Mobius MLP (fp32) ----
__global__ __launch_bounds__(256) void merge_mlp_kernel(
    const float* __restrict__ head, const float* __restrict__ tail,
    const float* __restrict__ nh_arr, const float* __restrict__ nt_arr,
    const float* __restrict__ Wm1, const float* __restrict__ bm1,
    const float* __restrict__ Wm2, const float* __restrict__ bm2,
    const float* __restrict__ Wm3, const float* __restrict__ bm3,
    float* __restrict__ out) {
    __shared__ float xs[256];
    __shared__ float red[256];
    const int row = blockIdx.x, tid = threadIdx.x;
    float h = head[(size_t)row * 256 + tid];
    float t = tail[(size_t)row * 256 + tid];
    float nh = nh_arr[row], ntl = nt_arr[row];
    float sh = tanhf(0.27f * artanh_c(nh)) / nh;
    float st = tanhf(0.73f * artanh_c(ntl)) / ntl;
    float A = sh * h, Bv = st * t;
    float x2 = block_reduce_sum(A * A, red);
    float y2 = block_reduce_sum(Bv * Bv, red);
    float xy = block_reduce_sum(A * Bv, red);
    float den = fmaxf(1.0f + 2.0f * xy + x2 * y2, 1e-15f);
    float z = ((1.0f + 2.0f * xy + y2) * A + (1.0f - x2) * Bv) / den;
    float nz = fmaxf(sqrtf(block_reduce_sum(z * z, red)), 1e-15f);
    float fz = (nz > MAXNORM_F) ? (MAXNORM_F / nz) : 1.0f;
    float nmid = nz * fz;
    xs[tid] = z * fz;
    __syncthreads();

    float v[1], bv[1];
    v[0] = 0.f; bv[0] = 0.f;
    if (tid < 64) {
        float acc = 0.f;
        for (int k = 0; k < 256; k++) acc += xs[k] * Wm1[k * 64 + tid];
        v[0] = acc; bv[0] = bm1[tid];
    }
    float n1 = hyper_head<1>(v, bv, 64, nmid, 1, red);
    __syncthreads();
    if (tid < 64) xs[tid] = v[0];
    __syncthreads();
    v[0] = 0.f; bv[0] = 0.f;
    if (tid < 32) {
        float acc = 0.f;
        for (int k = 0; k < 64; k++) acc += xs[k] * Wm2[k * 32 + tid];
        v[0] = acc; bv[0] = bm2[tid];
    }
    float n2 = hyper_head<1>(v, bv, 32, n1, 1, red);
    __syncthreads();
    if (tid < 32) xs[tid] = v[0];
    __syncthreads();
    v[0] = 0.f; bv[0] = 0.f;
    if (tid < 2) {
        float acc = 0.f;
        for (int k = 0; k < 32; k++) acc += xs[k] * Wm3[k * 2 + tid];
        v[0] = acc; bv[0] = bm3[tid];
    }
    hyper_head<1>(v, bv, 2, n2, 0, red);
    if (tid < 2) out[(size_t)row * 2 + tid] = v[0];
}

// ---- launch ----
extern "C" void kernel_launch(void* const* d_in, const int* in_sizes, int n_in,
                              void* d_out, int out_size, void* d_ws, size_t ws_size,
                              hipStream_t stream) {
    const float* dch = (const float*)d_in[0];
    const float* dpc = (const float*)d_in[1];
    const float* dmc = (const float*)d_in[2];
    const float* dec = (const float*)d_in[3];
    const float* tes = (const float*)d_in[4];
    const float* tpc = (const float*)d_in[5];
    const float* tme = (const float*)d_in[6];
    const float* Wd1 = (const float*)d_in[7];  const float* bd1 = (const float*)d_in[8];
    const float* Wd2 = (const float*)d_in[9];  const float* bd2 = (const float*)d_in[10];
    const float* Wd3 = (const float*)d_in[11]; const float* bd3 = (const float*)d_in[12];
    const float* Wt1 = (const float*)d_in[13]; const float* bt1 = (const float*)d_in[14];
    const float* Wt2 = (const float*)d_in[15]; const float* bt2 = (const float*)d_in[16];
    const float* Wt3 = (const float*)d_in[17]; const float* bt3 = (const float*)d_in[18];
    const float* Wm1 = (const float*)d_in[19]; const float* bm1 = (const float*)d_in[20];
    const float* Wm2 = (const float*)d_in[21]; const float* bm2 = (const float*)d_in[22];
    const float* Wm3 = (const float*)d_in[23]; const float* bm3 = (const float*)d_in[24];

    const int B = in_sizes[0] / 768;   // 16384

    float* mx  = (float*)d_ws;                          // B*1024 f32
    short* xb  = (short*)(mx + (size_t)B * 1024);       // B*3456 bf16 (shared both branches)
    float* hf_d = (float*)(xb + (size_t)B * 3456);      // B*256 f32
    float* hf_t = hf_d + (size_t)B * 256;
    float* xn_d = hf_t + (size_t)B * 256;
    float* xn_t = xn_d + B;
    short* wp_d1 = (short*)(xn_t + B);                  // 8*162*4096
    short* wp_d2 = wp_d1 + 8 * 162 * 4096;              // 4*96*4096
    short* wp_d3 = wp_d2 + 4 * 96 * 4096;               // 2*48*4096
    short* wp_t1 = wp_d3 + 2 * 48 * 4096;
    short* wp_t2 = wp_t1 + 8 * 162 * 4096;
    short* wp_t3 = wp_t2 + 4 * 96 * 4096;

    dim3 blk(256);
    int e1 = 8 * 162 * 4096, e2 = 4 * 96 * 4096, e3 = 2 * 48 * 4096;
    hipLaunchKernelGGL(pack_w_kernel, dim3((e1 + 255) / 256), blk, 0, stream, Wd1, 1711, 54, 162, 1024, wp_d1);
    hipLaunchKernelGGL(pack_w_kernel, dim3((e2 + 255) / 256), blk, 0, stream, Wd2, 1024, 32, 96, 512, wp_d2);
    hipLaunchKernelGGL(pack_w_kernel, dim3((e3 + 255) / 256), blk, 0, stream, Wd3, 512, 16, 48, 256, wp_d3);
    hipLaunchKernelGGL(pack_w_kernel, dim3((e1 + 255) / 256), blk, 0, stream, Wt1, 1711, 54, 162, 1024, wp_t1);
    hipLaunchKernelGGL(pack_w_kernel, dim3((e2 + 255) / 256), blk, 0, stream, Wt2, 1024, 32, 96, 512, wp_t2);
    hipLaunchKernelGGL(pack_w_kernel, dim3((e3 + 255) / 256), blk, 0, stream, Wt3, 512, 16, 48, 256, wp_t3);

    // ---- drug branch ----
    hipLaunchKernelGGL(prep_kernel, dim3(B), blk, 0, stream,
                       dch, dpc, dmc, dec, 768, 11, 167, 765, xb, xn_d);
    hipLaunchKernelGGL(gemm_mfma, dim3(8, B / 128), blk, 0, stream, xb, 3456, 54, wp_d1, 162, mx, 1024);
    hipLaunchKernelGGL((epi_kernel<4>), dim3(B), blk, 0, stream, mx, 1024, bd1, xn_d, xb, 2048, 1024, (float*)nullptr, 1);
    hipLaunchKernelGGL(gemm_mfma, dim3(4, B / 128), blk, 0, stream, xb, 2048, 32, wp_d2, 96, mx, 512);
    hipLaunchKernelGGL((epi_kernel<2>), dim3(B), blk, 0, stream, mx, 512, bd2, xn_d, xb, 1024, 512, (float*)nullptr, 1);
    hipLaunchKernelGGL(gemm_mfma, dim3(2, B / 128), blk, 0, stream, xb, 1024, 16, wp_d3, 48, mx, 256);
    hipLaunchKernelGGL((epi_kernel<1>), dim3(B), blk, 0, stream, mx, 256, bd3, xn_d, (short*)nullptr, 0, 0, hf_d, 0);

    // ---- target branch (reuses xb, mx) ----
    hipLaunchKernelGGL(prep_kernel, dim3(B), blk, 0, stream,
                       tes, tpc, tme, (const float*)nullptr, 1280, 11, 420, 0, xb, xn_t);
    hipLaunchKernelGGL(gemm_mfma, dim3(8, B / 128), blk, 0, stream, xb, 3456, 54, wp_t1, 162, mx, 1024);
    hipLaunchKernelGGL((epi_kernel<4>), dim3(B), blk, 0, stream, mx, 1024, bt1, xn_t, xb, 2048, 1024, (float*)nullptr, 1);
    hipLaunchKernelGGL(gemm_mfma, dim3(4, B / 128), blk, 0, stream, xb, 2048, 32, wp_t2, 96, mx, 512);
    hipLaunchKernelGGL((epi_kernel<2>), dim3(B), blk, 0, stream, mx, 512, bt2, xn_t, xb, 1024, 512, (float*)nullptr, 1);
    hipLaunchKernelGGL(gemm_mfma, dim3(2, B / 128), blk, 0, stream, xb, 1024, 16, wp_t3, 48, mx, 256);
    hipLaunchKernelGGL((epi_kernel<1>), dim3(B), blk, 0, stream, mx, 256, bt3, xn_t, (short*)nullptr, 0, 0, hf_t, 0);

    // ---- merge + MLP -> out ----
    hipLaunchKernelGGL(merge_mlp_kernel, dim3(B), blk, 0, stream,
                       hf_d, hf_t, xn_d, xn_t, Wm1, bm1, Wm2, bm2, Wm3, bm3, (float*)d_out);
}

// Round 4
// 1202.291 us; speedup vs baseline: 2.5538x; 1.4800x over previous
//
#include <hip/hip_runtime.h>
#include <math.h>

#define MAXNORM_F 0.996f

typedef __attribute__((ext_vector_type(8))) short bf16x8;
typedef __attribute__((ext_vector_type(4))) float f32x4;

__device__ __forceinline__ short f2bf(float f) {
    union { float f; unsigned u; } v; v.f = f;
    unsigned r = v.u + 0x7FFF + ((v.u >> 16) & 1);
    return (short)(r >> 16);
}
__device__ __forceinline__ float bf2f(short s) {
    union { unsigned u; float f; } v; v.u = ((unsigned)(unsigned short)s) << 16;
    return v.f;
}

__device__ __forceinline__ float artanh_c(float x) {
    const float lim = 1.0f - 1e-5f;
    x = fminf(fmaxf(x, -lim), lim);
    return 0.5f * logf((1.0f + x) / (1.0f - x));
}

// full 64-lane wave sum, result in all lanes
__device__ __forceinline__ float wsum(float v) {
#pragma unroll
    for (int m = 32; m > 0; m >>= 1) v += __shfl_xor(v, m, 64);
    return v;
}

// ---- weight pack: fp32 [K][N] -> bf16 [ntile][kb][seg(2:hi,lo)][kg(4)][n(128)][j(8)] ----
__global__ __launch_bounds__(256) void pack_w_kernel(
    const float* __restrict__ W, int Kreal, int KB, int N, short* __restrict__ out) {
    int e = blockIdx.x * 256 + threadIdx.x;
    int total = (N >> 7) * KB * 2 * 4096;
    if (e >= total) return;
    int j   = e & 7;
    int n   = (e >> 3) & 127;
    int kg  = (e >> 10) & 3;
    int seg = (e >> 12) & 1;
    int rest = e >> 13;
    int kb  = rest % KB;
    int nt  = rest / KB;
    int k = (kb << 5) + (kg << 3) + j;
    int col = (nt << 7) + n;
    float v = (k < Kreal) ? W[(size_t)k * N + col] : 0.f;
    short hi = f2bf(v);
    out[e] = (seg == 0) ? hi : f2bf(v - bf2f(hi));
}

// ---- prep: zscore + concat + expmap0 -> bf16 hi|lo split row. Wave-per-row. ----
__global__ __launch_bounds__(256) void prep_kernel(
    const float* __restrict__ s0, const float* __restrict__ s1,
    const float* __restrict__ s2, const float* __restrict__ s3,
    int f0, int f1, int f2, int f3,
    short* __restrict__ Xb, float* __restrict__ xn_out) {
    __shared__ float xbuf[4][1712];
    const int lane = threadIdx.x & 63, wave = threadIdx.x >> 6;
    const int row = blockIdx.x * 4 + wave;
    float* xb = xbuf[wave];
    const float* srcs[4] = {s0, s1, s2, s3};
    const int fs[4] = {f0, f1, f2, f3};
    int off = 0;
    for (int b = 0; b < 4; b++) {
        int F = fs[b];
        if (F == 0) break;
        const float* srow = srcs[b] + (size_t)row * F;
        float ps = 0.f;
        for (int i = lane; i < F; i += 64) { float v = srow[i]; xb[off + i] = v; ps += v; }
        float mean = wsum(ps) / (float)F;
        float pq = 0.f;
        for (int i = lane; i < F; i += 64) { float d = xb[off + i] - mean; pq += d * d; }
        float var = wsum(pq) / (float)(F - 1);
        float inv = 1.0f / (sqrtf(var) + 1e-8f);
        for (int i = lane; i < F; i += 64) xb[off + i] = (xb[off + i] - mean) * inv;
        off += F;
    }
    float pn = 0.f;
    for (int i = lane; i < 1711; i += 64) pn += xb[i] * xb[i];
    float n = fmaxf(sqrtf(wsum(pn)), 1e-15f);
    float t = tanhf(n);
    float sc = t / n;
    short* xrow = Xb + (size_t)row * 3456;   // [hi(1728) | lo(1728)]
    for (int i = lane; i < 1711; i += 64) {
        float v = sc * xb[i];
        short hi = f2bf(v);
        xrow[i] = hi;
        xrow[1728 + i] = f2bf(v - bf2f(hi));
    }
    if (lane < 17) { xrow[1711 + lane] = 0; xrow[1728 + 1711 + lane] = 0; }
    if (lane == 0) xn_out[row] = fmaxf(t, 1e-15f);
}

// ---- bf16 MFMA GEMM, fused 3-term split precision ----
// A: bf16 [M][lda], lda = 2*Kpad (hi | lo halves). Wp packed per pack_w_kernel.
// Per K-block: stage Ah,Al,Wh,Wl once; sweep Ah*Wh + Al*Wh + Ah*Wl (48 MFMA / barrier).
__global__ __launch_bounds__(256) void gemm_mfma(
    const short* __restrict__ A, int lda, int KB,
    const short* __restrict__ Wp,
    float* __restrict__ C, int N) {
    __shared__ short Ah[4096], Al[4096], Bh[4096], Bl[4096];
    const int tid = threadIdx.x;
    const int lane = tid & 63;
    const int wave = __builtin_amdgcn_readfirstlane(tid >> 6);
    const int waveM = wave >> 1, waveN = wave & 1;
    const int m0 = blockIdx.y * 128;
    const int kg = lane >> 4, l16 = lane & 15;
    const int Kpad = lda >> 1;

    f32x4 acc[4][4] = {};
    const short* Bbase = Wp + (size_t)blockIdx.x * KB * 8192;

    for (int kb = 0; kb < KB; kb++) {
#pragma unroll
        for (int c2 = 0; c2 < 2; c2++) {
            int c = wave * 2 + c2;
            int u = c * 64 + lane;
            int row = u >> 2;
            int k8 = (u & 3) ^ (row & 3);
            const short* ga = A + (size_t)(m0 + row) * lda + (kb << 5) + (k8 << 3);
            __builtin_amdgcn_global_load_lds(
                (const __attribute__((address_space(1))) unsigned int*)ga,
                (__attribute__((address_space(3))) unsigned int*)&Ah[c * 512], 16, 0, 0);
            __builtin_amdgcn_global_load_lds(
                (const __attribute__((address_space(1))) unsigned int*)(ga + Kpad),
                (__attribute__((address_space(3))) unsigned int*)&Al[c * 512], 16, 0, 0);
        }
#pragma unroll
        for (int c2 = 0; c2 < 2; c2++) {
            int c = wave * 2 + c2;
            const short* gb = Bbase + (size_t)kb * 8192 + c * 512 + lane * 8;
            __builtin_amdgcn_global_load_lds(
                (const __attribute__((address_space(1))) unsigned int*)gb,
                (__attribute__((address_space(3))) unsigned int*)&Bh[c * 512], 16, 0, 0);
            __builtin_amdgcn_global_load_lds(
                (const __attribute__((address_space(1))) unsigned int*)(gb + 4096),
                (__attribute__((address_space(3))) unsigned int*)&Bl[c * 512], 16, 0, 0);
        }
        __syncthreads();
        bf16x8 ah[4], al[4], bh[4], bl[4];
#pragma unroll
        for (int mi = 0; mi < 4; mi++) {
            int row = waveM * 64 + mi * 16 + l16;
            int u = row * 4 + (kg ^ (row & 3));
            ah[mi] = *(const bf16x8*)&Ah[u * 8];
            al[mi] = *(const bf16x8*)&Al[u * 8];
        }
#pragma unroll
        for (int ni = 0; ni < 4; ni++) {
            int n = waveN * 64 + ni * 16 + l16;
            bh[ni] = *(const bf16x8*)&Bh[(kg * 128 + n) * 8];
            bl[ni] = *(const bf16x8*)&Bl[(kg * 128 + n) * 8];
        }
#pragma unroll
        for (int mi = 0; mi < 4; mi++)
#pragma unroll
            for (int ni = 0; ni < 4; ni++)
                acc[mi][ni] = __builtin_amdgcn_mfma_f32_16x16x32_bf16(ah[mi], bh[ni], acc[mi][ni], 0, 0, 0);
#pragma unroll
        for (int mi = 0; mi < 4; mi++)
#pragma unroll
            for (int ni = 0; ni < 4; ni++)
                acc[mi][ni] = __builtin_amdgcn_mfma_f32_16x16x32_bf16(al[mi], bh[ni], acc[mi][ni], 0, 0, 0);
#pragma unroll
        for (int mi = 0; mi < 4; mi++)
#pragma unroll
            for (int ni = 0; ni < 4; ni++)
                acc[mi][ni] = __builtin_amdgcn_mfma_f32_16x16x32_bf16(ah[mi], bl[ni], acc[mi][ni], 0, 0, 0);
        __syncthreads();
    }
    const int rbase = m0 + waveM * 64 + (lane >> 4) * 4;
    const int cbase = blockIdx.x * 128 + waveN * 64 + l16;
#pragma unroll
    for (int mi = 0; mi < 4; mi++)
#pragma unroll
        for (int ni = 0; ni < 4; ni++)
#pragma unroll
            for (int r = 0; r < 4; r++)
                C[(size_t)(rbase + mi * 16 + r) * N + cbase + ni * 16] = acc[mi][ni][r];
}

// ---- hyperbolic linear head, wave-level, E elements per lane (zero-filled if inactive) ----
template<int E>
__device__ float hyper_head_w(float (&v)[E], const float (&bv)[E], float xn, int do_tanh) {
    float p = 0.f;
#pragma unroll
    for (int e = 0; e < E; e++) p += v[e] * v[e];
    float mxn = fmaxf(sqrtf(wsum(p)), 1e-15f);
    float t1 = tanhf((mxn / xn) * artanh_c(xn));
    float ny = fmaxf(t1, 1e-15f);
    float fac = (ny > MAXNORM_F) ? (MAXNORM_F / ny) : 1.0f;
    float sm = t1 * fac / mxn;
    float pa2 = 0.f, pab = 0.f, pb2 = 0.f;
#pragma unroll
    for (int e = 0; e < E; e++) {
        v[e] *= sm;
        pa2 += v[e] * v[e]; pab += v[e] * bv[e]; pb2 += bv[e] * bv[e];
    }
    float a2 = wsum(pa2);
    float ab = wsum(pab);
    float b2 = wsum(pb2);
    float den = fmaxf(1.0f + 2.0f * ab + a2 * b2, 1e-15f);
    float ca = (1.0f + 2.0f * ab + b2) / den;
    float cb = (1.0f - a2) / den;
    float pz2 = 0.f;
#pragma unroll
    for (int e = 0; e < E; e++) {
        v[e] = ca * v[e] + cb * bv[e];
        pz2 += v[e] * v[e];
    }
    float nz = fmaxf(sqrtf(wsum(pz2)), 1e-15f);
    float fz = (nz > MAXNORM_F) ? (MAXNORM_F / nz) : 1.0f;
    float nzp = nz * fz;
    if (!do_tanh) {
#pragma unroll
        for (int e = 0; e < E; e++) v[e] *= fz;
        return nzp;
    }
    float ia = artanh_c(nzp) / nzp * fz;
    float pt2 = 0.f;
#pragma unroll
    for (int e = 0; e < E; e++) {
        v[e] = tanhf(ia * v[e]);
        pt2 += v[e] * v[e];
    }
    float ntn = fmaxf(sqrtf(wsum(pt2)), 1e-15f);
    float to = tanhf(ntn);
    float no = fmaxf(to, 1e-15f);
    float fo = (no > MAXNORM_F) ? (MAXNORM_F / no) : 1.0f;
    float so = to / ntn * fo;
#pragma unroll
    for (int e = 0; e < E; e++) v[e] *= so;
    return fminf(no, MAXNORM_F);
}

// ---- epilogue: wave-per-row, 4 rows/block. N = VPT*256. ----
template<int VPT>
__global__ __launch_bounds__(256) void epi_kernel(
    const float* __restrict__ MX, int N, const float* __restrict__ bias,
    float* __restrict__ xn_io, short* __restrict__ Xout, int ldx, int off,
    float* __restrict__ Fout, int do_tanh) {
    const int lane = threadIdx.x & 63, wave = threadIdx.x >> 6;
    const int row = blockIdx.x * 4 + wave;
    const float* mrow = MX + (size_t)row * N;
    float v[4 * VPT], bv[4 * VPT];
#pragma unroll
    for (int j = 0; j < VPT; j++) {
        int idx = j * 256 + lane * 4;
        float4 t = *(const float4*)(mrow + idx);
        v[4 * j] = t.x; v[4 * j + 1] = t.y; v[4 * j + 2] = t.z; v[4 * j + 3] = t.w;
        float4 tb = *(const float4*)(bias + idx);
        bv[4 * j] = tb.x; bv[4 * j + 1] = tb.y; bv[4 * j + 2] = tb.z; bv[4 * j + 3] = tb.w;
    }
    float xn = xn_io[row];
    float nrm = hyper_head_w<4 * VPT>(v, bv, xn, do_tanh);
    if (Xout) {
        short* orow = Xout + (size_t)row * ldx;
#pragma unroll
        for (int j = 0; j < VPT; j++) {
            int idx = j * 256 + lane * 4;
            short4 h4, l4;
            short hi;
            hi = f2bf(v[4 * j + 0]); h4.x = hi; l4.x = f2bf(v[4 * j + 0] - bf2f(hi));
            hi = f2bf(v[4 * j + 1]); h4.y = hi; l4.y = f2bf(v[4 * j + 1] - bf2f(hi));
            hi = f2bf(v[4 * j + 2]); h4.z = hi; l4.z = f2bf(v[4 * j + 2] - bf2f(hi));
            hi = f2bf(v[4 * j + 3]); h4.w = hi; l4.w = f2bf(v[4 * j + 3] - bf2f(hi));
            *(short4*)(orow + idx) = h4;
            *(short4*)(orow + off + idx) = l4;
        }
    }
    if (Fout) {
        float* orow = Fout + (size_t)row * N;
#pragma unroll
        for (int j = 0; j < VPT; j++) {
            int idx = j * 256 + lane * 4;
            float4 t;
            t.x = v[4 * j]; t.y = v[4 * j + 1]; t.z = v[4 * j + 2]; t.w = v[4 * j + 3];
            *(float4*)(orow + idx) = t;
        }
    }
    if (lane == 0) xn_io[row] = fmaxf(nrm, 1e-15f);
}

// ---- merge + 3-layer Mobius MLP, wave-per-row ----
__global__ __launch_bounds__(256) void merge_mlp_kernel(
    const float* __restrict__ head, const float* __restrict__ tail,
    const float* __restrict__ nh_arr, const float* __restrict__ nt_arr,
    const float* __restrict__ Wm1, const float* __restrict__ bm1,
    const float* __restrict__ Wm2, const float* __restrict__ bm2,
    const float* __restrict__ Wm3, const float* __restrict__ bm3,
    float* __restrict__ out) {
    __shared__ float xs[4][256];
    const int lane = threadIdx.x & 63, wave = threadIdx.x >> 6;
    const int row = blockIdx.x * 4 + wave;
    float* x = xs[wave];
    float4 h4 = *(const float4*)(head + (size_t)row * 256 + lane * 4);
    float4 t4 = *(const float4*)(tail + (size_t)row * 256 + lane * 4);
    float A[4] = {h4.x, h4.y, h4.z, h4.w};
    float Bv[4] = {t4.x, t4.y, t4.z, t4.w};
    float nh = nh_arr[row], ntl = nt_arr[row];
    float sh = tanhf(0.27f * artanh_c(nh)) / nh;
    float st = tanhf(0.73f * artanh_c(ntl)) / ntl;
    float px2 = 0.f, py2 = 0.f, pxy = 0.f;
#pragma unroll
    for (int e = 0; e < 4; e++) {
        A[e] *= sh; Bv[e] *= st;
        px2 += A[e] * A[e]; py2 += Bv[e] * Bv[e]; pxy += A[e] * Bv[e];
    }
    float x2 = wsum(px2), y2 = wsum(py2), xy = wsum(pxy);
    float den = fmaxf(1.0f + 2.0f * xy + x2 * y2, 1e-15f);
    float ca = (1.0f + 2.0f * xy + y2) / den, cb = (1.0f - x2) / den;
    float z[4]; float pz2 = 0.f;
#pragma unroll
    for (int e = 0; e < 4; e++) { z[e] = ca * A[e] + cb * Bv[e]; pz2 += z[e] * z[e]; }
    float nz = fmaxf(sqrtf(wsum(pz2)), 1e-15f);
    float fz = (nz > MAXNORM_F) ? (MAXNORM_F / nz) : 1.0f;
    float nmid = nz * fz;
    float4 zs; zs.x = z[0] * fz; zs.y = z[1] * fz; zs.z = z[2] * fz; zs.w = z[3] * fz;
    *(float4*)(x + lane * 4) = zs;

    // layer 1: 256 -> 64, tanh (all 64 lanes active)
    float v[1], bvv[1];
    {
        float acc = 0.f;
        for (int k = 0; k < 256; k++) acc += x[k] * Wm1[k * 64 + lane];
        v[0] = acc; bvv[0] = bm1[lane];
    }
    float n1 = hyper_head_w<1>(v, bvv, nmid, 1);
    x[lane] = v[0];
    // layer 2: 64 -> 32, tanh
    {
        float acc = 0.f;
        if (lane < 32) { for (int k = 0; k < 64; k++) acc += x[k] * Wm2[k * 32 + lane]; }
        v[0] = (lane < 32) ? acc : 0.f;
        bvv[0] = (lane < 32) ? bm2[lane] : 0.f;
    }
    float n2 = hyper_head_w<1>(v, bvv, n1, 1);
    x[lane] = (lane < 32) ? v[0] : 0.f;
    // layer 3: 32 -> 2, no tanh
    {
        float acc = 0.f;
        if (lane < 2) { for (int k = 0; k < 32; k++) acc += x[k] * Wm3[k * 2 + lane]; }
        v[0] = (lane < 2) ? acc : 0.f;
        bvv[0] = (lane < 2) ? bm3[lane] : 0.f;
    }
    hyper_head_w<1>(v, bvv, n2, 0);
    if (lane < 2) out[(size_t)row * 2 + lane] = v[0];
}

// ---- launch ----
extern "C" void kernel_launch(void* const* d_in, const int* in_sizes, int n_in,
                              void* d_out, int out_size, void* d_ws, size_t ws_size,
                              hipStream_t stream) {
    const float* dch = (const float*)d_in[0];
    const float* dpc = (const float*)d_in[1];
    const float* dmc = (const float*)d_in[2];
    const float* dec = (const float*)d_in[3];
    const float* tes = (const float*)d_in[4];
    const float* tpc = (const float*)d_in[5];
    const float* tme = (const float*)d_in[6];
    const float* Wd1 = (const float*)d_in[7];  const float* bd1 = (const float*)d_in[8];
    const float* Wd2 = (const float*)d_in[9];  const float* bd2 = (const float*)d_in[10];
    const float* Wd3 = (const float*)d_in[11]; const float* bd3 = (const float*)d_in[12];
    const float* Wt1 = (const float*)d_in[13]; const float* bt1 = (const float*)d_in[14];
    const float* Wt2 = (const float*)d_in[15]; const float* bt2 = (const float*)d_in[16];
    const float* Wt3 = (const float*)d_in[17]; const float* bt3 = (const float*)d_in[18];
    const float* Wm1 = (const float*)d_in[19]; const float* bm1 = (const float*)d_in[20];
    const float* Wm2 = (const float*)d_in[21]; const float* bm2 = (const float*)d_in[22];
    const float* Wm3 = (const float*)d_in[23]; const float* bm3 = (const float*)d_in[24];

    const int B = in_sizes[0] / 768;   // 16384

    float* mx  = (float*)d_ws;                          // B*1024 f32
    short* xb  = (short*)(mx + (size_t)B * 1024);       // B*3456 bf16 (shared both branches)
    float* hf_d = (float*)(xb + (size_t)B * 3456);      // B*256 f32
    float* hf_t = hf_d + (size_t)B * 256;
    float* xn_d = hf_t + (size_t)B * 256;
    float* xn_t = xn_d + B;
    // packed weights: [ntile][KB][2][4096] shorts
    short* wp_d1 = (short*)(xn_t + B);                  // 8*54*8192
    short* wp_d2 = wp_d1 + 8 * 54 * 8192;               // 4*32*8192
    short* wp_d3 = wp_d2 + 4 * 32 * 8192;               // 2*16*8192
    short* wp_t1 = wp_d3 + 2 * 16 * 8192;
    short* wp_t2 = wp_t1 + 8 * 54 * 8192;
    short* wp_t3 = wp_t2 + 4 * 32 * 8192;

    dim3 blk(256);
    int e1 = 8 * 54 * 8192, e2 = 4 * 32 * 8192, e3 = 2 * 16 * 8192;
    hipLaunchKernelGGL(pack_w_kernel, dim3((e1 + 255) / 256), blk, 0, stream, Wd1, 1711, 54, 1024, wp_d1);
    hipLaunchKernelGGL(pack_w_kernel, dim3((e2 + 255) / 256), blk, 0, stream, Wd2, 1024, 32, 512, wp_d2);
    hipLaunchKernelGGL(pack_w_kernel, dim3((e3 + 255) / 256), blk, 0, stream, Wd3, 512, 16, 256, wp_d3);
    hipLaunchKernelGGL(pack_w_kernel, dim3((e1 + 255) / 256), blk, 0, stream, Wt1, 1711, 54, 1024, wp_t1);
    hipLaunchKernelGGL(pack_w_kernel, dim3((e2 + 255) / 256), blk, 0, stream, Wt2, 1024, 32, 512, wp_t2);
    hipLaunchKernelGGL(pack_w_kernel, dim3((e3 + 255) / 256), blk, 0, stream, Wt3, 512, 16, 256, wp_t3);

    // ---- drug branch ----
    hipLaunchKernelGGL(prep_kernel, dim3(B / 4), blk, 0, stream,
                       dch, dpc, dmc, dec, 768, 11, 167, 765, xb, xn_d);
    hipLaunchKernelGGL(gemm_mfma, dim3(8, B / 128), blk, 0, stream, xb, 3456, 54, wp_d1, mx, 1024);
    hipLaunchKernelGGL((epi_kernel<4>), dim3(B / 4), blk, 0, stream, mx, 1024, bd1, xn_d, xb, 2048, 1024, (float*)nullptr, 1);
    hipLaunchKernelGGL(gemm_mfma, dim3(4, B / 128), blk, 0, stream, xb, 2048, 32, wp_d2, mx, 512);
    hipLaunchKernelGGL((epi_kernel<2>), dim3(B / 4), blk, 0, stream, mx, 512, bd2, xn_d, xb, 1024, 512, (float*)nullptr, 1);
    hipLaunchKernelGGL(gemm_mfma, dim3(2, B / 128), blk, 0, stream, xb, 1024, 16, wp_d3, mx, 256);
    hipLaunchKernelGGL((epi_kernel<1>), dim3(B / 4), blk, 0, stream, mx, 256, bd3, xn_d, (short*)nullptr, 0, 0, hf_d, 0);

    // ---- target branch (reuses xb, mx) ----
    hipLaunchKernelGGL(prep_kernel, dim3(B / 4), blk, 0, stream,
                       tes, tpc, tme, (const float*)nullptr, 1280, 11, 420, 0, xb, xn_t);
    hipLaunchKernelGGL(gemm_mfma, dim3(8, B / 128), blk, 0, stream, xb, 3456, 54, wp_t1, mx, 1024);
    hipLaunchKernelGGL((epi_kernel<4>), dim3(B / 4), blk, 0, stream, mx, 1024, bt1, xn_t, xb, 2048, 1024, (float*)nullptr, 1);
    hipLaunchKernelGGL(gemm_mfma, dim3(4, B / 128), blk, 0, stream, xb, 2048, 32, wp_t2, mx, 512);
    hipLaunchKernelGGL((epi_kernel<2>), dim3(B / 4), blk, 0, stream, mx, 512, bt2, xn_t, xb, 1024, 512, (float*)nullptr, 1);
    hipLaunchKernelGGL(gemm_mfma, dim3(2, B / 128), blk, 0, stream, xb, 1024, 16, wp_t3, mx, 256);
    hipLaunchKernelGGL((epi_kernel<1>), dim3(B / 4), blk, 0, stream, mx, 256, bt3, xn_t, (short*)nullptr, 0, 0, hf_t, 0);

    // ---- merge + MLP -> out ----
    hipLaunchKernelGGL(merge_mlp_kernel, dim3(B / 4), blk, 0, stream,
                       hf_d, hf_t, xn_d, xn_t, Wm1, bm1, Wm2, bm2, Wm3, bm3, (float*)d_out);
}

// Round 5
// 1072.879 us; speedup vs baseline: 2.8619x; 1.1206x over previous
//
#include <hip/hip_runtime.h>
#include <math.h>

#define MAXNORM_F 0.996f

typedef __attribute__((ext_vector_type(8))) short bf16x8;
typedef __attribute__((ext_vector_type(4))) float f32x4;

__device__ __forceinline__ short f2bf(float f) {
    union { float f; unsigned u; } v; v.f = f;
    unsigned r = v.u + 0x7FFF + ((v.u >> 16) & 1);
    return (short)(r >> 16);
}
__device__ __forceinline__ float bf2f(short s) {
    union { unsigned u; float f; } v; v.u = ((unsigned)(unsigned short)s) << 16;
    return v.f;
}

__device__ __forceinline__ float artanh_c(float x) {
    const float lim = 1.0f - 1e-5f;
    x = fminf(fmaxf(x, -lim), lim);
    return 0.5f * logf((1.0f + x) / (1.0f - x));
}

// full 64-lane wave sum, result in all lanes
__device__ __forceinline__ float wsum(float v) {
#pragma unroll
    for (int m = 32; m > 0; m >>= 1) v += __shfl_xor(v, m, 64);
    return v;
}

// ---- weight pack: fp32 [K][N] -> bf16 [ntile][kb][seg(2:hi,lo)][kg(4)][n(128)][j(8)] ----
__global__ __launch_bounds__(256) void pack_w_kernel(
    const float* __restrict__ W, int Kreal, int KB, int N, short* __restrict__ out) {
    int e = blockIdx.x * 256 + threadIdx.x;
    int total = (N >> 7) * KB * 2 * 4096;
    if (e >= total) return;
    int j   = e & 7;
    int n   = (e >> 3) & 127;
    int kg  = (e >> 10) & 3;
    int seg = (e >> 12) & 1;
    int rest = e >> 13;
    int kb  = rest % KB;
    int nt  = rest / KB;
    int k = (kb << 5) + (kg << 3) + j;
    int col = (nt << 7) + n;
    float v = (k < Kreal) ? W[(size_t)k * N + col] : 0.f;
    short hi = f2bf(v);
    out[e] = (seg == 0) ? hi : f2bf(v - bf2f(hi));
}

// ---- prep: zscore + concat + expmap0 -> bf16, interleaved [kb][hi32|lo32]. Wave-per-row. ----
__global__ __launch_bounds__(256) void prep_kernel(
    const float* __restrict__ s0, const float* __restrict__ s1,
    const float* __restrict__ s2, const float* __restrict__ s3,
    int f0, int f1, int f2, int f3,
    short* __restrict__ Xb, float* __restrict__ xn_out) {
    __shared__ float xbuf[4][1712];
    const int lane = threadIdx.x & 63, wave = threadIdx.x >> 6;
    const int row = blockIdx.x * 4 + wave;
    float* xb = xbuf[wave];
    const float* srcs[4] = {s0, s1, s2, s3};
    const int fs[4] = {f0, f1, f2, f3};
    int off = 0;
    for (int b = 0; b < 4; b++) {
        int F = fs[b];
        if (F == 0) break;
        const float* srow = srcs[b] + (size_t)row * F;
        float ps = 0.f;
        for (int i = lane; i < F; i += 64) { float v = srow[i]; xb[off + i] = v; ps += v; }
        float mean = wsum(ps) / (float)F;
        float pq = 0.f;
        for (int i = lane; i < F; i += 64) { float d = xb[off + i] - mean; pq += d * d; }
        float var = wsum(pq) / (float)(F - 1);
        float inv = 1.0f / (sqrtf(var) + 1e-8f);
        for (int i = lane; i < F; i += 64) xb[off + i] = (xb[off + i] - mean) * inv;
        off += F;
    }
    float pn = 0.f;
    for (int i = lane; i < 1711; i += 64) pn += xb[i] * xb[i];
    float n = fmaxf(sqrtf(wsum(pn)), 1e-15f);
    float t = tanhf(n);
    float sc = t / n;
    short* xrow = Xb + (size_t)row * 3456;   // [kb(54)][hi(32)|lo(32)]
    for (int i = lane; i < 1728; i += 64) {
        float v = (i < 1711) ? sc * xb[i] : 0.f;
        short hi = f2bf(v);
        int base = (i >> 5) * 64 + (i & 31);
        xrow[base] = hi;
        xrow[base + 32] = f2bf(v - bf2f(hi));
    }
    if (lane == 0) xn_out[row] = fmaxf(t, 1e-15f);
}

// ---- bf16 MFMA GEMM, fused 3-term split precision, line-dense A, XCD swizzle ----
// A: bf16 [M][lda], lda = 2*Kpad, layout [kb][hi32|lo32] per row (128B lines).
// Wp packed per pack_w_kernel. Grid: 1D, NT*M/128 blocks, NT = 1<<ntShift.
__global__ __launch_bounds__(256) void gemm_mfma(
    const short* __restrict__ A, int lda, int KB,
    const short* __restrict__ Wp,
    float* __restrict__ C, int N, int ntShift) {
    __shared__ short As[8192];  // 128 rows x 64 shorts; 16B-unit slot = p ^ (row&7)
    __shared__ short Bs[8192];  // [seg(2)][kg(4)][n(128)][j(8)]
    const int tid = threadIdx.x;
    const int lane = tid & 63;
    const int wave = __builtin_amdgcn_readfirstlane(tid >> 6);
    const int waveM = wave >> 1, waveN = wave & 1;
    const int kg = lane >> 4, l16 = lane & 15;

    // XCD-aware swizzle: same m-strip -> same XCD, consecutive in time
    int flat = blockIdx.x;
    int xcd = flat & 7;
    int idx = flat >> 3;
    int q = idx >> ntShift;
    int nt = idx & ((1 << ntShift) - 1);
    int mt = q * 8 + xcd;
    const int m0 = mt * 128;

    f32x4 acc[4][4] = {};
    const short* Bbase = Wp + (size_t)nt * KB * 8192;

    for (int kb = 0; kb < KB; kb++) {
        // stage A: 1024 x 16B units; unit u holds chunk p = (u&7)^(row&7) of row u>>3
#pragma unroll
        for (int c = 0; c < 4; c++) {
            int u = c * 256 + wave * 64 + lane;
            int row = u >> 3;
            int p = (u & 7) ^ (row & 7);
            const short* ga = A + (size_t)(m0 + row) * lda + kb * 64 + p * 8;
            __builtin_amdgcn_global_load_lds(
                (const __attribute__((address_space(1))) unsigned int*)ga,
                (__attribute__((address_space(3))) unsigned int*)&As[(c * 256 + wave * 64) * 8],
                16, 0, 0);
        }
        // stage B: 1024 units, fully linear
#pragma unroll
        for (int c = 0; c < 4; c++) {
            int u = c * 256 + wave * 64 + lane;
            const short* gb = Bbase + (size_t)kb * 8192 + u * 8;
            __builtin_amdgcn_global_load_lds(
                (const __attribute__((address_space(1))) unsigned int*)gb,
                (__attribute__((address_space(3))) unsigned int*)&Bs[(c * 256 + wave * 64) * 8],
                16, 0, 0);
        }
        __syncthreads();
        bf16x8 ah[4], al[4], bh[4], bl[4];
#pragma unroll
        for (int mi = 0; mi < 4; mi++) {
            int r = waveM * 64 + mi * 16 + l16;
            int uh = r * 8 + (kg ^ (r & 7));
            int ul = r * 8 + ((4 + kg) ^ (r & 7));
            ah[mi] = *(const bf16x8*)&As[uh * 8];
            al[mi] = *(const bf16x8*)&As[ul * 8];
        }
#pragma unroll
        for (int ni = 0; ni < 4; ni++) {
            int n = waveN * 64 + ni * 16 + l16;
            bh[ni] = *(const bf16x8*)&Bs[(kg * 128 + n) * 8];
            bl[ni] = *(const bf16x8*)&Bs[(512 + kg * 128 + n) * 8];
        }
#pragma unroll
        for (int mi = 0; mi < 4; mi++)
#pragma unroll
            for (int ni = 0; ni < 4; ni++)
                acc[mi][ni] = __builtin_amdgcn_mfma_f32_16x16x32_bf16(ah[mi], bh[ni], acc[mi][ni], 0, 0, 0);
#pragma unroll
        for (int mi = 0; mi < 4; mi++)
#pragma unroll
            for (int ni = 0; ni < 4; ni++)
                acc[mi][ni] = __builtin_amdgcn_mfma_f32_16x16x32_bf16(al[mi], bh[ni], acc[mi][ni], 0, 0, 0);
#pragma unroll
        for (int mi = 0; mi < 4; mi++)
#pragma unroll
            for (int ni = 0; ni < 4; ni++)
                acc[mi][ni] = __builtin_amdgcn_mfma_f32_16x16x32_bf16(ah[mi], bl[ni], acc[mi][ni], 0, 0, 0);
        __syncthreads();
    }
    const int rbase = m0 + waveM * 64 + (lane >> 4) * 4;
    const int cbase = nt * 128 + waveN * 64 + l16;
#pragma unroll
    for (int mi = 0; mi < 4; mi++)
#pragma unroll
        for (int ni = 0; ni < 4; ni++)
#pragma unroll
            for (int r = 0; r < 4; r++)
                C[(size_t)(rbase + mi * 16 + r) * N + cbase + ni * 16] = acc[mi][ni][r];
}

// ---- hyperbolic linear head, wave-level, E elements per lane (zero-filled if inactive) ----
template<int E>
__device__ float hyper_head_w(float (&v)[E], const float (&bv)[E], float xn, int do_tanh) {
    float p = 0.f;
#pragma unroll
    for (int e = 0; e < E; e++) p += v[e] * v[e];
    float mxn = fmaxf(sqrtf(wsum(p)), 1e-15f);
    float t1 = tanhf((mxn / xn) * artanh_c(xn));
    float ny = fmaxf(t1, 1e-15f);
    float fac = (ny > MAXNORM_F) ? (MAXNORM_F / ny) : 1.0f;
    float sm = t1 * fac / mxn;
    float pa2 = 0.f, pab = 0.f, pb2 = 0.f;
#pragma unroll
    for (int e = 0; e < E; e++) {
        v[e] *= sm;
        pa2 += v[e] * v[e]; pab += v[e] * bv[e]; pb2 += bv[e] * bv[e];
    }
    float a2 = wsum(pa2);
    float ab = wsum(pab);
    float b2 = wsum(pb2);
    float den = fmaxf(1.0f + 2.0f * ab + a2 * b2, 1e-15f);
    float ca = (1.0f + 2.0f * ab + b2) / den;
    float cb = (1.0f - a2) / den;
    float pz2 = 0.f;
#pragma unroll
    for (int e = 0; e < E; e++) {
        v[e] = ca * v[e] + cb * bv[e];
        pz2 += v[e] * v[e];
    }
    float nz = fmaxf(sqrtf(wsum(pz2)), 1e-15f);
    float fz = (nz > MAXNORM_F) ? (MAXNORM_F / nz) : 1.0f;
    float nzp = nz * fz;
    if (!do_tanh) {
#pragma unroll
        for (int e = 0; e < E; e++) v[e] *= fz;
        return nzp;
    }
    float ia = artanh_c(nzp) / nzp * fz;
    float pt2 = 0.f;
#pragma unroll
    for (int e = 0; e < E; e++) {
        v[e] = tanhf(ia * v[e]);
        pt2 += v[e] * v[e];
    }
    float ntn = fmaxf(sqrtf(wsum(pt2)), 1e-15f);
    float to = tanhf(ntn);
    float no = fmaxf(to, 1e-15f);
    float fo = (no > MAXNORM_F) ? (MAXNORM_F / no) : 1.0f;
    float so = to / ntn * fo;
#pragma unroll
    for (int e = 0; e < E; e++) v[e] *= so;
    return fminf(no, MAXNORM_F);
}

// ---- epilogue: wave-per-row, 4 rows/block. N = VPT*256. Writes interleaved [kb][hi|lo]. ----
template<int VPT>
__global__ __launch_bounds__(256) void epi_kernel(
    const float* __restrict__ MX, int N, const float* __restrict__ bias,
    float* __restrict__ xn_io, short* __restrict__ Xout, int ldx,
    float* __restrict__ Fout, int do_tanh) {
    const int lane = threadIdx.x & 63, wave = threadIdx.x >> 6;
    const int row = blockIdx.x * 4 + wave;
    const float* mrow = MX + (size_t)row * N;
    float v[4 * VPT], bv[4 * VPT];
#pragma unroll
    for (int j = 0; j < VPT; j++) {
        int idx = j * 256 + lane * 4;
        float4 t = *(const float4*)(mrow + idx);
        v[4 * j] = t.x; v[4 * j + 1] = t.y; v[4 * j + 2] = t.z; v[4 * j + 3] = t.w;
        float4 tb = *(const float4*)(bias + idx);
        bv[4 * j] = tb.x; bv[4 * j + 1] = tb.y; bv[4 * j + 2] = tb.z; bv[4 * j + 3] = tb.w;
    }
    float xn = xn_io[row];
    float nrm = hyper_head_w<4 * VPT>(v, bv, xn, do_tanh);
    if (Xout) {
        short* orow = Xout + (size_t)row * ldx;
#pragma unroll
        for (int j = 0; j < VPT; j++) {
            int idx = j * 256 + lane * 4;
            int base = (idx >> 5) * 64 + (idx & 31);
            short4 h4, l4;
            short hi;
            hi = f2bf(v[4 * j + 0]); h4.x = hi; l4.x = f2bf(v[4 * j + 0] - bf2f(hi));
            hi = f2bf(v[4 * j + 1]); h4.y = hi; l4.y = f2bf(v[4 * j + 1] - bf2f(hi));
            hi = f2bf(v[4 * j + 2]); h4.z = hi; l4.z = f2bf(v[4 * j + 2] - bf2f(hi));
            hi = f2bf(v[4 * j + 3]); h4.w = hi; l4.w = f2bf(v[4 * j + 3] - bf2f(hi));
            *(short4*)(orow + base) = h4;
            *(short4*)(orow + base + 32) = l4;
        }
    }
    if (Fout) {
        float* orow = Fout + (size_t)row * N;
#pragma unroll
        for (int j = 0; j < VPT; j++) {
            int idx = j * 256 + lane * 4;
            float4 t;
            t.x = v[4 * j]; t.y = v[4 * j + 1]; t.z = v[4 * j + 2]; t.w = v[4 * j + 3];
            *(float4*)(orow + idx) = t;
        }
    }
    if (lane == 0) xn_io[row] = fmaxf(nrm, 1e-15f);
}

// ---- merge + 3-layer Mobius MLP, wave-per-row ----
__global__ __launch_bounds__(256) void merge_mlp_kernel(
    const float* __restrict__ head, const float* __restrict__ tail,
    const float* __restrict__ nh_arr, const float* __restrict__ nt_arr,
    const float* __restrict__ Wm1, const float* __restrict__ bm1,
    const float* __restrict__ Wm2, const float* __restrict__ bm2,
    const float* __restrict__ Wm3, const float* __restrict__ bm3,
    float* __restrict__ out) {
    __shared__ float xs[4][256];
    const int lane = threadIdx.x & 63, wave = threadIdx.x >> 6;
    const int row = blockIdx.x * 4 + wave;
    float* x = xs[wave];
    float4 h4 = *(const float4*)(head + (size_t)row * 256 + lane * 4);
    float4 t4 = *(const float4*)(tail + (size_t)row * 256 + lane * 4);
    float A[4] = {h4.x, h4.y, h4.z, h4.w};
    float Bv[4] = {t4.x, t4.y, t4.z, t4.w};
    float nh = nh_arr[row], ntl = nt_arr[row];
    float sh = tanhf(0.27f * artanh_c(nh)) / nh;
    float st = tanhf(0.73f * artanh_c(ntl)) / ntl;
    float px2 = 0.f, py2 = 0.f, pxy = 0.f;
#pragma unroll
    for (int e = 0; e < 4; e++) {
        A[e] *= sh; Bv[e] *= st;
        px2 += A[e] * A[e]; py2 += Bv[e] * Bv[e]; pxy += A[e] * Bv[e];
    }
    float x2 = wsum(px2), y2 = wsum(py2), xy = wsum(pxy);
    float den = fmaxf(1.0f + 2.0f * xy + x2 * y2, 1e-15f);
    float ca = (1.0f + 2.0f * xy + y2) / den, cb = (1.0f - x2) / den;
    float z[4]; float pz2 = 0.f;
#pragma unroll
    for (int e = 0; e < 4; e++) { z[e] = ca * A[e] + cb * Bv[e]; pz2 += z[e] * z[e]; }
    float nz = fmaxf(sqrtf(wsum(pz2)), 1e-15f);
    float fz = (nz > MAXNORM_F) ? (MAXNORM_F / nz) : 1.0f;
    float nmid = nz * fz;
    float4 zs; zs.x = z[0] * fz; zs.y = z[1] * fz; zs.z = z[2] * fz; zs.w = z[3] * fz;
    *(float4*)(x + lane * 4) = zs;

    float v[1], bvv[1];
    {
        float acc = 0.f;
        for (int k = 0; k < 256; k++) acc += x[k] * Wm1[k * 64 + lane];
        v[0] = acc; bvv[0] = bm1[lane];
    }
    float n1 = hyper_head_w<1>(v, bvv, nmid, 1);
    x[lane] = v[0];
    {
        float acc = 0.f;
        if (lane < 32) { for (int k = 0; k < 64; k++) acc += x[k] * Wm2[k * 32 + lane]; }
        v[0] = (lane < 32) ? acc : 0.f;
        bvv[0] = (lane < 32) ? bm2[lane] : 0.f;
    }
    float n2 = hyper_head_w<1>(v, bvv, n1, 1);
    x[lane] = (lane < 32) ? v[0] : 0.f;
    {
        float acc = 0.f;
        if (lane < 2) { for (int k = 0; k < 32; k++) acc += x[k] * Wm3[k * 2 + lane]; }
        v[0] = (lane < 2) ? acc : 0.f;
        bvv[0] = (lane < 2) ? bm3[lane] : 0.f;
    }
    hyper_head_w<1>(v, bvv, n2, 0);
    if (lane < 2) out[(size_t)row * 2 + lane] = v[0];
}

// ---- launch ----
extern "C" void kernel_launch(void* const* d_in, const int* in_sizes, int n_in,
                              void* d_out, int out_size, void* d_ws, size_t ws_size,
                              hipStream_t stream) {
    const float* dch = (const float*)d_in[0];
    const float* dpc = (const float*)d_in[1];
    const float* dmc = (const float*)d_in[2];
    const float* dec = (const float*)d_in[3];
    const float* tes = (const float*)d_in[4];
    const float* tpc = (const float*)d_in[5];
    const float* tme = (const float*)d_in[6];
    const float* Wd1 = (const float*)d_in[7];  const float* bd1 = (const float*)d_in[8];
    const float* Wd2 = (const float*)d_in[9];  const float* bd2 = (const float*)d_in[10];
    const float* Wd3 = (const float*)d_in[11]; const float* bd3 = (const float*)d_in[12];
    const float* Wt1 = (const float*)d_in[13]; const float* bt1 = (const float*)d_in[14];
    const float* Wt2 = (const float*)d_in[15]; const float* bt2 = (const float*)d_in[16];
    const float* Wt3 = (const float*)d_in[17]; const float* bt3 = (const float*)d_in[18];
    const float* Wm1 = (const float*)d_in[19]; const float* bm1 = (const float*)d_in[20];
    const float* Wm2 = (const float*)d_in[21]; const float* bm2 = (const float*)d_in[22];
    const float* Wm3 = (const float*)d_in[23]; const float* bm3 = (const float*)d_in[24];

    const int B = in_sizes[0] / 768;   // 16384

    float* mx  = (float*)d_ws;                          // B*1024 f32
    short* xb  = (short*)(mx + (size_t)B * 1024);       // B*3456 bf16 (shared both branches)
    float* hf_d = (float*)(xb + (size_t)B * 3456);      // B*256 f32
    float* hf_t = hf_d + (size_t)B * 256;
    float* xn_d = hf_t + (size_t)B * 256;
    float* xn_t = xn_d + B;
    // packed weights: [ntile][KB][2][4096] shorts
    short* wp_d1 = (short*)(xn_t + B);                  // 8*54*8192
    short* wp_d2 = wp_d1 + 8 * 54 * 8192;               // 4*32*8192
    short* wp_d3 = wp_d2 + 4 * 32 * 8192;               // 2*16*8192
    short* wp_t1 = wp_d3 + 2 * 16 * 8192;
    short* wp_t2 = wp_t1 + 8 * 54 * 8192;
    short* wp_t3 = wp_t2 + 4 * 32 * 8192;

    dim3 blk(256);
    int e1 = 8 * 54 * 8192, e2 = 4 * 32 * 8192, e3 = 2 * 16 * 8192;
    hipLaunchKernelGGL(pack_w_kernel, dim3((e1 + 255) / 256), blk, 0, stream, Wd1, 1711, 54, 1024, wp_d1);
    hipLaunchKernelGGL(pack_w_kernel, dim3((e2 + 255) / 256), blk, 0, stream, Wd2, 1024, 32, 512, wp_d2);
    hipLaunchKernelGGL(pack_w_kernel, dim3((e3 + 255) / 256), blk, 0, stream, Wd3, 512, 16, 256, wp_d3);
    hipLaunchKernelGGL(pack_w_kernel, dim3((e1 + 255) / 256), blk, 0, stream, Wt1, 1711, 54, 1024, wp_t1);
    hipLaunchKernelGGL(pack_w_kernel, dim3((e2 + 255) / 256), blk, 0, stream, Wt2, 1024, 32, 512, wp_t2);
    hipLaunchKernelGGL(pack_w_kernel, dim3((e3 + 255) / 256), blk, 0, stream, Wt3, 512, 16, 256, wp_t3);

    // ---- drug branch ----
    hipLaunchKernelGGL(prep_kernel, dim3(B / 4), blk, 0, stream,
                       dch, dpc, dmc, dec, 768, 11, 167, 765, xb, xn_d);
    hipLaunchKernelGGL(gemm_mfma, dim3(8 * (B / 128)), blk, 0, stream, xb, 3456, 54, wp_d1, mx, 1024, 3);
    hipLaunchKernelGGL((epi_kernel<4>), dim3(B / 4), blk, 0, stream, mx, 1024, bd1, xn_d, xb, 2048, (float*)nullptr, 1);
    hipLaunchKernelGGL(gemm_mfma, dim3(4 * (B / 128)), blk, 0, stream, xb, 2048, 32, wp_d2, mx, 512, 2);
    hipLaunchKernelGGL((epi_kernel<2>), dim3(B / 4), blk, 0, stream, mx, 512, bd2, xn_d, xb, 1024, (float*)nullptr, 1);
    hipLaunchKernelGGL(gemm_mfma, dim3(2 * (B / 128)), blk, 0, stream, xb, 1024, 16, wp_d3, mx, 256, 1);
    hipLaunchKernelGGL((epi_kernel<1>), dim3(B / 4), blk, 0, stream, mx, 256, bd3, xn_d, (short*)nullptr, 0, hf_d, 0);

    // ---- target branch (reuses xb, mx) ----
    hipLaunchKernelGGL(prep_kernel, dim3(B / 4), blk, 0, stream,
                       tes, tpc, tme, (const float*)nullptr, 1280, 11, 420, 0, xb, xn_t);
    hipLaunchKernelGGL(gemm_mfma, dim3(8 * (B / 128)), blk, 0, stream, xb, 3456, 54, wp_t1, mx, 1024, 3);
    hipLaunchKernelGGL((epi_kernel<4>), dim3(B / 4), blk, 0, stream, mx, 1024, bt1, xn_t, xb, 2048, (float*)nullptr, 1);
    hipLaunchKernelGGL(gemm_mfma, dim3(4 * (B / 128)), blk, 0, stream, xb, 2048, 32, wp_t2, mx, 512, 2);
    hipLaunchKernelGGL((epi_kernel<2>), dim3(B / 4), blk, 0, stream, mx, 512, bt2, xn_t, xb, 1024, (float*)nullptr, 1);
    hipLaunchKernelGGL(gemm_mfma, dim3(2 * (B / 128)), blk, 0, stream, xb, 1024, 16, wp_t3, mx, 256, 1);
    hipLaunchKernelGGL((epi_kernel<1>), dim3(B / 4), blk, 0, stream, mx, 256, bt3, xn_t, (short*)nullptr, 0, hf_t, 0);

    // ---- merge + MLP -> out ----
    hipLaunchKernelGGL(merge_mlp_kernel, dim3(B / 4), blk, 0, stream,
                       hf_d, hf_t, xn_d, xn_t, Wm1, bm1, Wm2, bm2, Wm3, bm3, (float*)d_out);
}